// Round 6
// baseline (249.505 us; speedup 1.0000x reference)
//
#include <hip/hip_runtime.h>
#include <math.h>

// Non-explicit FP stays separate mul/add; explicit fma models the reference's
// contraction (XLA CPU AllowFPOpFusion::Fast). NUMERICS FROZEN SINCE R3:
// absmax 1.117587e-08. All structural forms here are bit-identical
// per-element and HW-VALIDATED (identical absmax) across R7(R1)/R9/R10/R11:
//  - packed skew A (ap[28]): lower = exact IEEE negation of upper, diag +0;
//    l1 skips the diag +0 no-op add. [R7, R11]
//  - A2 mirror is BITWISE equal: term k of A2[j][i] is (-A[k][j])*(-A[i][k])
//    == A[i][k]*A[k][j], same k-order. A4 same argument over symmetric A2;
//    packed a4p[36] scalar chains validated in R7. A6=A4*A2 NOT symmetric.
//  - combine writes W->w6, V->a2 in place (same values, storage only).
//  - U from ±ap broadcasts, c-outer streamed, folded P=U+V / Q=V-U in place:
//    identical chains (loop order only reorders independent elements). [R7]
//  - swap/updates restricted to LIVE Q column-pairs (lanes j<k hold dead L).
//  - gram upper+x2 weighting: bitwise-symmetric gram; only final f32 sum
//    order changes — established invisible.
// REGISTER STRATEGY (hard lessons R4/R6/R7(old) + R9/R10/R11):
//  - Occupancy cliff ABOVE 128 VGPR: 132/136-VGPR builds run 10.3-10.7%
//    occupancy vs 18.5% at 128 (120-126us vs 88us). MUST be <=128.
//  - Free allocator refuses to land <=128 on restructured code (136,136,132
//    across R9/R10/R11) even with data peak ~96 VGPRs — it spends slack on
//    scheduling. So IMPOSE the cap: empirical toolchain mapping (old R4/R6)
//    is __launch_bounds__(256,2) -> cap 128, (256,3) -> 84. Old-shape (256,2)
//    spilled 43MB because data peak alone was 128 VGPRs; THIS shape's peak is
//    ~96 (ap28+a2 64+a4p36+w6 64 = 192 floats), leaving ~30 regs headroom.
//  - TRIPWIRE: WRITE_SIZE >> 64KB means spill -> revert to R0 next round.
#pragma clang fp contract(off)

typedef float f2 __attribute__((ext_vector_type(2)));

static __device__ __forceinline__ f2 sp(float x) { f2 r; r.x = x; r.y = x; return r; }
static __device__ __forceinline__ f2 sel2(bool d, f2 a, f2 b) {
  f2 r; r.x = d ? a.x : b.x; r.y = d ? a.y : b.y; return r;
}
#define FMA2(A, B, C) __builtin_elementwise_fma((A), (B), (C))

// element access into row-major f2-packed 8x8: m[i*4 + (j>>1)] lane (j&1)
#define EL(m, i, j) (m[(i)*4 + ((j) >> 1)][(j) & 1])

// strict-upper packed index (28 entries), i<j, compile-time after unroll
#define UA(i, j) ((((i) * (15 - (i))) / 2) + (j) - (i) - 1)
// upper-incl-diag packed index (36 entries), j>=i
#define U4(i, j) ((((i) * (17 - (i))) / 2) + (j) - (i))
#define A4P(i, k) ((i) <= (k) ? a4p[U4(i, k)] : a4p[U4(k, i)])
// skew A element from packed ap (negation folds into consumer's modifier)
#define ELA(i, k) ((i) < (k) ? ap[UA(i, k)] : ((i) > (k) ? -ap[UA(k, i)] : 0.0f))

// Full 8x8 matmul, fmaf k-chain, f2-paired over j. Used by the rare squaring
// path only. Bitwise == R5's scalar mm8 (full 8-term chains, first term mul).
__device__ __forceinline__ void mm8p(const f2* __restrict__ A,
                                     const f2* __restrict__ B,
                                     f2* __restrict__ C) {
  #pragma unroll
  for (int i = 0; i < 8; ++i) {
    #pragma unroll
    for (int c = 0; c < 4; ++c) {
      f2 s = sp(EL(A, i, 0)) * B[0*4 + c];
      #pragma unroll
      for (int k = 1; k < 8; ++k)
        s = FMA2(sp(EL(A, i, k)), B[k*4 + c], s);
      C[i*4 + c] = s;
    }
  }
}

// One thread per 8x8 block, 256-thread workgroups. (256,2): empirical VGPR
// cap 128 on this toolchain — binds the allocator exactly at the occupancy
// cliff. Data live-set peak ~96 VGPRs leaves ~30 for temps: no-spill expected.
__global__ __launch_bounds__(256, 2)
void triality_kernel(const float* __restrict__ in, double* __restrict__ acc)
{
  const int t = blockIdx.x * 256 + threadIdx.x;
  const float4* src = (const float4*)(in + (size_t)t * 64);

  float p[64];
  #pragma unroll
  for (int i = 0; i < 16; ++i) {
    float4 q4 = src[i];
    p[4*i+0] = q4.x; p[4*i+1] = q4.y; p[4*i+2] = q4.z; p[4*i+3] = q4.w;
  }

  // packed strict-upper skew part: ap[UA(i,j)] = 0.5*(p_ij - p_ji), i<j.
  float ap[28];
  #pragma unroll
  for (int i = 0; i < 8; ++i)
    #pragma unroll
    for (int j = i + 1; j < 8; ++j)
      ap[UA(i, j)] = 0.5f * (p[i*8 + j] - p[j*8 + i]);

  // 1-norm: per column j, ascending i (diag +0 add was a no-op; |-x|==|x|),
  // then running max — identical op order to R5 (validated R7/R11).
  float l1 = 0.0f;
  #pragma unroll
  for (int j = 0; j < 8; ++j) {
    float cs = 0.0f;
    #pragma unroll
    for (int i = 0; i < 8; ++i) {
      if (i < j)      cs = cs + fabsf(ap[UA(i, j)]);
      else if (i > j) cs = cs + fabsf(ap[UA(j, i)]);
    }
    l1 = fmaxf(l1, cs);
  }

  // n_squarings = max(0, floor(log2(A_L1 / 3.925724783138660)))
  float fl = floorf(log2f(l1 / 3.925724783138660f));
  int ns = (fl > 0.0f) ? (int)fl : 0;
  if (ns > 0) {
    float sc = exp2f((float)(-ns));   // exact power of two
    #pragma unroll
    for (int m = 0; m < 28; ++m) ap[m] = ap[m] * sc;   // (-u)*sc == -(u*sc)
  }

  // transient full skew A (f2 rows) — only the A2 matmul reads it; dies after.
  f2 af[32];
  #pragma unroll
  for (int i = 0; i < 8; ++i)
    #pragma unroll
    for (int j = 0; j < 8; ++j)
      EL(af, i, j) = (i < j) ? ap[UA(i, j)]
                   : ((i > j) ? -ap[UA(j, i)] : 0.0f);

  // A2 = A*A (bitwise symmetric): compute f2 pairs with 2c+1 >= i, mirror the
  // 12 fully-lower pairs. Full 8-term fmaf chains, j-paired — chains == R5.
  f2 a2[32];
  #pragma unroll
  for (int i = 0; i < 8; ++i)
    #pragma unroll
    for (int c = 0; c < 4; ++c) {
      if (2*c + 1 >= i) {
        f2 s = sp(EL(af, i, 0)) * af[0*4 + c];
        #pragma unroll
        for (int k = 1; k < 8; ++k)
          s = FMA2(sp(EL(af, i, k)), af[k*4 + c], s);
        a2[i*4 + c] = s;
      }
    }
  #pragma unroll
  for (int i = 0; i < 8; ++i)
    #pragma unroll
    for (int c = 0; c < 4; ++c)
      if (2*c + 1 < i) {
        EL(a2, i, 2*c)     = EL(a2, 2*c,     i);
        EL(a2, i, 2*c + 1) = EL(a2, 2*c + 1, i);
      }

  // A4 = A2*A2 (bitwise symmetric): packed 36 scalars, full 8-term chains,
  // first term mul, k ascending — identical chain per element (R7-validated).
  float a4p[36];
  #pragma unroll
  for (int i = 0; i < 8; ++i)
    #pragma unroll
    for (int j = i; j < 8; ++j) {
      float s = EL(a2, i, 0) * EL(a2, 0, j);
      #pragma unroll
      for (int k = 1; k < 8; ++k)
        s = __builtin_fmaf(EL(a2, i, k), EL(a2, k, j), s);
      a4p[U4(i, j)] = s;
    }

  // A6 = A4*A2 (full — not bitwise symmetric). A4 broadcasts read packed.
  f2 w6[32];
  #pragma unroll
  for (int i = 0; i < 8; ++i)
    #pragma unroll
    for (int c = 0; c < 4; ++c) {
      f2 s = sp(A4P(i, 0)) * a2[0*4 + c];
      #pragma unroll
      for (int k = 1; k < 8; ++k)
        s = FMA2(sp(A4P(i, k)), a2[k*4 + c], s);
      w6[i*4 + c] = s;
    }

  // XLA backend-fused polynomial combine (validated R3), j-paired, in place:
  //   W = fma(277200, A2, fma(1512, A4, A6)) + diag(8648640)    -> w6
  //   V = fma(1995840, A2, fma(56, A6, 25200*A4)) + diag(17297280) -> a2
  #pragma unroll
  for (int i = 0; i < 8; ++i)
    #pragma unroll
    for (int c = 0; c < 4; ++c) {
      f2 x2 = a2[i*4 + c], x6 = w6[i*4 + c];
      f2 x4; x4.x = A4P(i, 2*c); x4.y = A4P(i, 2*c + 1);
      f2 w = FMA2(sp(1512.0f), x4, x6);
      w = FMA2(sp(277200.0f), x2, w);
      f2 v = FMA2(sp(56.0f), x6, sp(25200.0f) * x4);
      v = FMA2(sp(1995840.0f), x2, v);
      w6[i*4 + c] = w;   // W
      a2[i*4 + c] = v;   // V
    }
  #pragma unroll
  for (int i = 0; i < 8; ++i) {   // diagonal adds (scalar halves)
    EL(w6, i, i) = EL(w6, i, i) + 8648640.0f;
    EL(a2, i, i) = EL(a2, i, i) + 17297280.0f;
  }

  // U = A @ W from packed ap broadcasts, c-outer streamed (W column c dies
  // after its pass; P/Q columns born), folded P=U+V -> pp, Q=V-U -> a2.
  // Per-element chains identical to the separate form (R7/R11-validated).
  f2 pp[32];
  #pragma unroll
  for (int c = 0; c < 4; ++c)
    #pragma unroll
    for (int i = 0; i < 8; ++i) {
      f2 s = sp(ELA(i, 0)) * w6[0*4 + c];
      #pragma unroll
      for (int k = 1; k < 8; ++k)
        s = FMA2(sp(ELA(i, k)), w6[k*4 + c], s);
      f2 V = a2[i*4 + c];
      pp[i*4 + c] = s + V;   // P = U + V
      a2[i*4 + c] = V - s;   // Q = V - U
    }
  f2* P = pp;
  f2* Q = a2;

  // ---- fused augmented elimination on [Q|P]: getrf(Q) + laswp(P) +
  // unit-lower trsm, interleaved per step k (bit-identical to the separate
  // passes). Swap is IN-PLACE progressive (d true at most once), restricted
  // to LIVE Q column-pairs (c >= k>>1) + all P columns.
  #pragma unroll
  for (int k = 0; k < 8; ++k) {
    float amax = fabsf(EL(Q, k, k)); int jp = k;
    #pragma unroll
    for (int i = k + 1; i < 8; ++i) {
      float av = fabsf(EL(Q, i, k));
      if (av > amax) { amax = av; jp = i; }   // first max, like isamax
    }
    const int c0 = k >> 1;
    #pragma unroll
    for (int i = k + 1; i < 8; ++i) {
      bool d = (jp == i);
      #pragma unroll
      for (int c = c0; c < 4; ++c) {
        f2 qk = Q[k*4 + c], qi = Q[i*4 + c];
        Q[k*4 + c] = sel2(d, qi, qk);
        Q[i*4 + c] = sel2(d, qk, qi);
      }
      #pragma unroll
      for (int c = 0; c < 4; ++c) {
        f2 pk_ = P[k*4 + c], pi = P[i*4 + c];
        P[k*4 + c] = sel2(d, pi, pk_);
        P[i*4 + c] = sel2(d, pk_, pi);
      }
    }

    // pivot-column scale: direct IEEE divide (validated R3)
    float dk = EL(Q, k, k);
    #pragma unroll
    for (int i = k + 1; i < 8; ++i) EL(Q, i, k) = EL(Q, i, k) / dk;
    // trailing updates: Q as pk pairs over live columns (lik read first;
    // corrupted lanes j<=k are dead L storage) + P row-axpy (pk).
    #pragma unroll
    for (int i = k + 1; i < 8; ++i) {
      float lik = EL(Q, i, k);
      f2 nl = sp(-lik);
      #pragma unroll
      for (int c = c0; c < 4; ++c)
        Q[i*4 + c] = FMA2(nl, Q[k*4 + c], Q[i*4 + c]);
      #pragma unroll
      for (int c = 0; c < 4; ++c)
        P[i*4 + c] = FMA2(nl, P[k*4 + c], P[i*4 + c]);
    }
  }

  // strsm: non-unit upper, k descending, IEEE f32 divide per element
  #pragma unroll
  for (int k = 7; k >= 0; --k) {
    float dk = EL(Q, k, k);
    #pragma unroll
    for (int j = 0; j < 8; ++j) EL(P, k, j) = EL(P, k, j) / dk;
    #pragma unroll
    for (int i = 0; i < k; ++i) {
      f2 nu = sp(-EL(Q, i, k));
      #pragma unroll
      for (int c = 0; c < 4; ++c)
        P[i*4 + c] = FMA2(nu, P[k*4 + c], P[i*4 + c]);
    }
  }

  // repeated squaring (ns in {0,1} statistically)
  for (int sq = 0; sq < ns; ++sq) {
    f2 t2[32];
    mm8p(P, P, t2);
    #pragma unroll
    for (int e = 0; e < 32; ++e) P[e] = t2[e];
  }

  // gram = R^T R - I: bitwise symmetric -> compute pairs with 2c+1 >= i,
  // weight off-diag x2 (exact doubling), diag x1, duplicate-lower-lane x0.
  // Per-element chains identical; only the f32 sum order differs (invisible;
  // HW-validated R7/R9/R10/R11).
  f2 s2p = sp(0.0f);
  #pragma unroll
  for (int i = 0; i < 8; ++i) {
    #pragma unroll
    for (int c = 0; c < 4; ++c) {
      if (2*c + 1 >= i) {
        f2 g = sp(EL(P, 0, i)) * P[0*4 + c];
        #pragma unroll
        for (int j = 1; j < 8; ++j)
          g = FMA2(sp(EL(P, j, i)), P[j*4 + c], g);
        f2 idv; idv.x = (2*c == i) ? 1.0f : 0.0f;
        idv.y = (2*c + 1 == i) ? 1.0f : 0.0f;
        f2 e = g - idv;
        f2 we;
        we.x = (2*c > i) ? (e.x + e.x) : ((2*c == i) ? e.x : 0.0f);
        we.y = (2*c + 1 == i) ? e.y : (e.y + e.y);
        s2p = FMA2(we, e, s2p);
      }
    }
  }
  float frob = sqrtf(s2p.x + s2p.y);

  // wave shuffle reduce (f64) -> LDS -> one atomic per 256-thread block
  double dv = (double)frob;
  #pragma unroll
  for (int off = 32; off > 0; off >>= 1)
    dv += __shfl_down(dv, off);

  __shared__ double part[4];
  const int lane = threadIdx.x & 63;
  const int wid  = threadIdx.x >> 6;
  if (lane == 0) part[wid] = dv;
  __syncthreads();
  if (threadIdx.x == 0) {
    double s = (part[0] + part[1]) + (part[2] + part[3]);
    atomicAdd(acc, s);
  }
}

__global__ void finalize_kernel(const double* __restrict__ acc,
                                float* __restrict__ out, int nmat)
{
  out[0] = (float)(acc[0] / (double)nmat);
}

extern "C" void kernel_launch(void* const* d_in, const int* in_sizes, int n_in,
                              void* d_out, int out_size, void* d_ws, size_t ws_size,
                              hipStream_t stream) {
  const float* in = (const float*)d_in[0];
  float* out = (float*)d_out;
  double* acc = (double*)d_ws;
  int nmat = in_sizes[0] / 64;   // 524288
  hipMemsetAsync(d_ws, 0, sizeof(double), stream);
  triality_kernel<<<nmat / 256, 256, 0, stream>>>(in, acc);
  finalize_kernel<<<1, 1, 0, stream>>>(acc, out, nmat);
}

// Round 7
// 214.275 us; speedup vs baseline: 1.1644x; 1.1644x over previous
//
#include <hip/hip_runtime.h>
#include <math.h>

// Non-explicit FP stays separate mul/add; explicit fma models the reference's
// contraction (XLA CPU AllowFPOpFusion::Fast). NUMERICS FROZEN SINCE R3:
// absmax 1.117587e-08. Every change since is bit-identical per-element:
//  - v_pk_{fma,add,mul,sub}_f32 round each 32-bit lane exactly like scalar.
//  - fused augmented elimination == getrf+laswp+trsm bitwise (swaps carry full
//    rows; row k is physically final after step k; each logical row receives
//    identical multiplier*pivotrow updates in identical k-order).
//  - err-sum reordering perturbs the f64 mean by ~1e-13 (invisible; absmax
//    was bit-stable across the R4/R6 reorders).
//
// SESSION LEDGER (R7-R12 exploration, all falsified on HW — do not retry):
//  - Restructured instruction-cut builds (sym A2/A4 mirrors, folded U->P/Q,
//    live-column elimination, weighted gram): bit-exact (absmax identical)
//    but free allocator lands 132-136 VGPR -> above the 128 occupancy cliff
//    (occ 18.5%->10.4%, dur 88->120-126us). The ~8% instruction cut is worth
//    ~7us; the occupancy loss costs ~35us. Net loss.
//  - amdgpu_waves_per_eu(5): clamps to 48 VGPR, 1.2GB spill, 541us.
//  - __launch_bounds__(256,2) cap=128 on the restructured shape: binds at
//    128 and restores occupancy but spills ~160B/thread (WRITE 84MB), 121us.
//  - Data-live-set shrink (ap[28] packed skew A, a4p[36]): allocator still
//    used 132. Cannot coax it under the cliff by shrinking data.
// => R0 structure at 128 VGPR / free allocator is a measured local optimum.
// Next unexplored lever (from this anchor only): 2-lane cooperative split.
#pragma clang fp contract(off)

typedef float f2 __attribute__((ext_vector_type(2)));

static __device__ __forceinline__ f2 sp(float x) { f2 r; r.x = x; r.y = x; return r; }
#define FMA2(A, B, C) __builtin_elementwise_fma((A), (B), (C))

// element access into row-major f2-packed 8x8: m[i*4 + (j>>1)] lane (j&1)
#define EL(m, i, j) (m[(i)*4 + ((j) >> 1)][(j) & 1])

// Full 8x8 matmul, fmaf k-chain, f2-paired over j. Bitwise == R5's scalar mm8
// (full 8-term chains; first term is a mul). Used by the rare squaring path.
__device__ __forceinline__ void mm8p(const f2* __restrict__ A,
                                     const f2* __restrict__ B,
                                     f2* __restrict__ C) {
  #pragma unroll
  for (int i = 0; i < 8; ++i) {
    #pragma unroll
    for (int c = 0; c < 4; ++c) {
      f2 s = sp(EL(A, i, 0)) * B[0*4 + c];
      #pragma unroll
      for (int k = 1; k < 8; ++k)
        s = FMA2(sp(EL(A, i, k)), B[k*4 + c], s);
      C[i*4 + c] = s;
    }
  }
}

// One thread per 8x8 block, 256-thread workgroups, NO min-waves bound:
// R4 (256,3)->VGPR 84 and R6 (256,2)->VGPR 128 both forced scratch spill
// (677MB / 43MB HBM write traffic). (256,1) leaves the allocator free; R5
// measured 132 VGPR, zero spill, on the same dataflow shape.
__global__ __launch_bounds__(256, 1)
void triality_kernel(const float* __restrict__ in, double* __restrict__ acc)
{
  const int t = blockIdx.x * 256 + threadIdx.x;
  const float4* src = (const float4*)(in + (size_t)t * 64);

  float p[64];
  #pragma unroll
  for (int i = 0; i < 16; ++i) {
    float4 q4 = src[i];
    p[4*i+0] = q4.x; p[4*i+1] = q4.y; p[4*i+2] = q4.z; p[4*i+3] = q4.w;
  }

  // A = 0.5*(P - P^T), all 64 entries each with its own sub+mul (R5 exact;
  // diag = +0 exactly).
  f2 aa[32];
  #pragma unroll
  for (int i = 0; i < 8; ++i)
    #pragma unroll
    for (int j = 0; j < 8; ++j)
      EL(aa, i, j) = 0.5f * (p[i*8+j] - p[j*8+i]);

  // 1-norm: per column j, cs = sum_i |a[i][j]| in ascending i (incl. diag +0),
  // then running max — identical op order to R5.
  float l1 = 0.0f;
  #pragma unroll
  for (int j = 0; j < 8; ++j) {
    float cs = 0.0f;
    #pragma unroll
    for (int i = 0; i < 8; ++i) cs = cs + fabsf(EL(aa, i, j));
    l1 = fmaxf(l1, cs);
  }

  // n_squarings = max(0, floor(log2(A_L1 / 3.925724783138660)))
  float fl = floorf(log2f(l1 / 3.925724783138660f));
  int ns = (fl > 0.0f) ? (int)fl : 0;
  if (ns > 0) {
    f2 sc = sp(exp2f((float)(-ns)));   // exact power of two
    #pragma unroll
    for (int e = 0; e < 32; ++e) aa[e] = aa[e] * sc;   // pk_mul, per-lane exact
  }

  // A2 = A*A  (full 8-term fmaf chains, j-paired)
  f2 a2[32];
  #pragma unroll
  for (int i = 0; i < 8; ++i)
    #pragma unroll
    for (int c = 0; c < 4; ++c) {
      f2 s = sp(EL(aa, i, 0)) * aa[0*4 + c];
      #pragma unroll
      for (int k = 1; k < 8; ++k)
        s = FMA2(sp(EL(aa, i, k)), aa[k*4 + c], s);
      a2[i*4 + c] = s;
    }

  // A4 = A2*A2
  f2 a4[32];
  #pragma unroll
  for (int i = 0; i < 8; ++i)
    #pragma unroll
    for (int c = 0; c < 4; ++c) {
      f2 s = sp(EL(a2, i, 0)) * a2[0*4 + c];
      #pragma unroll
      for (int k = 1; k < 8; ++k)
        s = FMA2(sp(EL(a2, i, k)), a2[k*4 + c], s);
      a4[i*4 + c] = s;
    }

  // A6 = A4*A2
  f2 w6[32];
  #pragma unroll
  for (int i = 0; i < 8; ++i)
    #pragma unroll
    for (int c = 0; c < 4; ++c) {
      f2 s = sp(EL(a4, i, 0)) * a2[0*4 + c];
      #pragma unroll
      for (int k = 1; k < 8; ++k)
        s = FMA2(sp(EL(a4, i, k)), a2[k*4 + c], s);
      w6[i*4 + c] = s;
    }

  // XLA backend-fused polynomial combine (validated R3), j-paired:
  //   W = fma(277200, A2, fma(1512, A4, A6)) + diag(8648640)   (into w6)
  //   V = fma(1995840, A2, fma(56, A6, 25200*A4)) + diag(17297280)
  f2 vv[32];
  #pragma unroll
  for (int e = 0; e < 32; ++e) {
    f2 x6 = w6[e], x4 = a4[e], x2 = a2[e];
    f2 w = FMA2(sp(1512.0f), x4, x6);
    w = FMA2(sp(277200.0f), x2, w);
    f2 v = FMA2(sp(56.0f), x6, sp(25200.0f) * x4);
    v = FMA2(sp(1995840.0f), x2, v);
    w6[e] = w; vv[e] = v;
  }
  #pragma unroll
  for (int i = 0; i < 8; ++i) {   // diagonal adds (scalar halves)
    EL(w6, i, i) = EL(w6, i, i) + 8648640.0f;
    EL(vv, i, i) = EL(vv, i, i) + 17297280.0f;
  }

  // U = A @ W  (full chains; k==i term is fmaf(+-0,y,s)==s — R5-equivalent)
  f2 uu[32];
  #pragma unroll
  for (int i = 0; i < 8; ++i)
    #pragma unroll
    for (int c = 0; c < 4; ++c) {
      f2 s = sp(EL(aa, i, 0)) * w6[0*4 + c];
      #pragma unroll
      for (int k = 1; k < 8; ++k)
        s = FMA2(sp(EL(aa, i, k)), w6[k*4 + c], s);
      uu[i*4 + c] = s;
    }

  // P = U + V (into uu), Q = V - U (into vv) — pk add/sub, per-lane exact
  #pragma unroll
  for (int e = 0; e < 32; ++e) {
    f2 U = uu[e], V = vv[e];
    uu[e] = U + V;
    vv[e] = V - U;
  }
  f2* P = uu;
  f2* Q = vv;

  // ---- fused augmented elimination on [Q|P]: getrf(Q) + laswp(P) +
  // unit-lower trsm, interleaved per step k (bit-identical to the separate
  // passes — see header comment). piv[] eliminated; L dies at step k.
  #pragma unroll
  for (int k = 0; k < 8; ++k) {
    float amax = fabsf(EL(Q, k, k)); int jp = k;
    #pragma unroll
    for (int i = k+1; i < 8; ++i) {
      float av = fabsf(EL(Q, i, k));
      if (av > amax) { amax = av; jp = i; }   // first max, like isamax
    }
    // swap rows k<->jp of BOTH Q and P (16-wide augmented row)
    #pragma unroll
    for (int i = k+1; i < 8; ++i) {
      bool d = (jp == i);
      #pragma unroll
      for (int j = 0; j < 8; ++j) {
        float x = EL(Q, k, j), y = EL(Q, i, j);
        EL(Q, k, j) = d ? y : x;
        EL(Q, i, j) = d ? x : y;
        float px = EL(P, k, j), py = EL(P, i, j);
        EL(P, k, j) = d ? py : px;
        EL(P, i, j) = d ? px : py;
      }
    }
    // pivot-column scale: direct IEEE divide (validated R3)
    float dk = EL(Q, k, k);
    #pragma unroll
    for (int i = k+1; i < 8; ++i) EL(Q, i, k) = EL(Q, i, k) / dk;
    // trailing updates: Q rank-1 (scalar) + P row-axpy (pk, independent elems)
    #pragma unroll
    for (int i = k+1; i < 8; ++i) {
      float lik = EL(Q, i, k);
      #pragma unroll
      for (int j = k+1; j < 8; ++j)
        EL(Q, i, j) = __builtin_fmaf(-lik, EL(Q, k, j), EL(Q, i, j));
      f2 nl = sp(-lik);
      #pragma unroll
      for (int c = 0; c < 4; ++c)
        P[i*4 + c] = FMA2(nl, P[k*4 + c], P[i*4 + c]);
    }
  }

  // strsm: non-unit upper, k descending, IEEE f32 divide per element
  #pragma unroll
  for (int k = 7; k >= 0; --k) {
    float dk = EL(Q, k, k);
    #pragma unroll
    for (int j = 0; j < 8; ++j) EL(P, k, j) = EL(P, k, j) / dk;
    #pragma unroll
    for (int i = 0; i < k; ++i) {
      f2 nu = sp(-EL(Q, i, k));
      #pragma unroll
      for (int c = 0; c < 4; ++c)
        P[i*4 + c] = FMA2(nu, P[k*4 + c], P[i*4 + c]);
    }
  }

  // repeated squaring (ns in {0,1} statistically)
  for (int sq = 0; sq < ns; ++sq) {
    f2 t2[32];
    mm8p(P, P, t2);
    #pragma unroll
    for (int e = 0; e < 32; ++e) P[e] = t2[e];
  }

  // gram = R^T R - I, sum of squares (full 64; pk-paired over kk).
  // Per-element chains identical to validated scalar; accumulation order
  // differs only in the final sum (invisible at threshold scale).
  f2 s2p = sp(0.0f);
  #pragma unroll
  for (int i = 0; i < 8; ++i) {
    #pragma unroll
    for (int c = 0; c < 4; ++c) {
      f2 g = sp(EL(P, 0, i)) * P[0*4 + c];
      #pragma unroll
      for (int j = 1; j < 8; ++j)
        g = FMA2(sp(EL(P, j, i)), P[j*4 + c], g);
      f2 idv; idv.x = (2*c == i) ? 1.0f : 0.0f; idv.y = (2*c + 1 == i) ? 1.0f : 0.0f;
      f2 e = g - idv;
      s2p = FMA2(e, e, s2p);
    }
  }
  float frob = sqrtf(s2p.x + s2p.y);

  // wave shuffle reduce (f64) -> LDS -> one atomic per 256-thread block
  double dv = (double)frob;
  #pragma unroll
  for (int off = 32; off > 0; off >>= 1)
    dv += __shfl_down(dv, off);

  __shared__ double part[4];
  const int lane = threadIdx.x & 63;
  const int wid  = threadIdx.x >> 6;
  if (lane == 0) part[wid] = dv;
  __syncthreads();
  if (threadIdx.x == 0) {
    double s = (part[0] + part[1]) + (part[2] + part[3]);
    atomicAdd(acc, s);
  }
}

__global__ void finalize_kernel(const double* __restrict__ acc,
                                float* __restrict__ out, int nmat)
{
  out[0] = (float)(acc[0] / (double)nmat);
}

extern "C" void kernel_launch(void* const* d_in, const int* in_sizes, int n_in,
                              void* d_out, int out_size, void* d_ws, size_t ws_size,
                              hipStream_t stream) {
  const float* in = (const float*)d_in[0];
  float* out = (float*)d_out;
  double* acc = (double*)d_ws;
  int nmat = in_sizes[0] / 64;   // 524288
  hipMemsetAsync(d_ws, 0, sizeof(double), stream);
  triality_kernel<<<nmat / 256, 256, 0, stream>>>(in, acc);
  finalize_kernel<<<1, 1, 0, stream>>>(acc, out, nmat);
}